// Round 1
// baseline (1087.862 us; speedup 1.0000x reference)
//
#include <hip/hip_runtime.h>
#include <math.h>

#define E_    3
#define QE_   60000
#define QTOT  180000      // E_*QE_
#define P_    40
#define H_    20
#define NIMG_ 1800
#define NNZ_  14400000
#define BLK   256
#define NB    704         // ceil(QTOT/BLK)

// column-window partition for the sparse force accumulation (fallback path)
#define CW_BITS 12
#define CW      4096                  // cols per window (16 KB LDS accumulator)
#define NBIN    132                   // ceil(3*QTOT / CW)
#define SUBS    8                     // sub-slices per bin in force kernel
#define SC      8192                  // nnz items per chunk
#define NSB     1758                  // ceil(NNZ_/SC)  (input chunking)

// row-slice partition: 131072 dE rows = 512 KB per slice -> fits XCD L2
#define SLICE_SHIFT 17
#define NSLICE  55                    // ceil(7.2M / 131072)
#define CAPS    270336                // per-slice item capacity (33*SC, +16 sigma)
#define CAPB    114688                // per-bin bm capacity (+16 sigma) [fallback]
#define MAXCH4  1815                  // 55*33 chunk slots
#define FS_GRID 768                   // fscatter4 blocks (3/CU) [fallback]
#define FS_PERX 96                    // blocks per XCD group   [fallback]

// v5: direct atomic scatter into per-XCD force replicas
#define FSZ      540000               // 3*QTOT floats per replica
#define NREP     8                    // one replica per XCD
#define FS_GRID2 2048                 // 8 blocks/CU, XCD-pinned
#define FS_PERX2 256                  // blocks per XCD group

// ctrl int offsets
#define C_SCUR  0      // [55]   slice cursors (= counts after slice_scatter)
#define C_BCUR  64     // [132]  bin cursors   (fallback path only)
#define C_GCNT  256    // [8]    per-XCD-group chunk counts
#define C_CHS   512    // [1815] chunk -> slice
#define C_CHST  2432   // [1815] chunk -> item start index
#define C_CHLEN 4352   // [1815] chunk -> length
#define C_GRP   6272   // [8*256] per-XCD-group chunk lists
#define C_INTS  8320

typedef int   vi4 __attribute__((ext_vector_type(4)));
typedef float vf4 __attribute__((ext_vector_type(4)));
typedef unsigned uint32;

// ---------------- zero init -------------------------------------------------
__global__ void zero_kernel(float* __restrict__ out, int n) {
    int i = blockIdx.x * blockDim.x + threadIdx.x;
    if (i < n) out[i] = 0.0f;
}
__global__ void zero_ctrl_kernel(int* __restrict__ ctrl) {
    ctrl[threadIdx.x] = 0;   // zeros C_SCUR + C_BCUR (first 256 ints)
}

// ---------------- stable counting sort for atom ranks ----------------------
__global__ void hist_kernel(const int* __restrict__ img, int* __restrict__ g_hist) {
    __shared__ int h[NIMG_];
    const int t = threadIdx.x, b = blockIdx.x;
    for (int v = t; v < NIMG_; v += BLK) h[v] = 0;
    __syncthreads();
    int a = b * BLK + t;
    if (a < QTOT) atomicAdd(&h[img[a]], 1);
    __syncthreads();
    for (int v = t; v < NIMG_; v += BLK) g_hist[v * NB + b] = h[v];
}

__global__ void scan_blocks_kernel(int* __restrict__ g_hist, int* __restrict__ g_total) {
    __shared__ int s[BLK];
    const int v = blockIdx.x, t = threadIdx.x;
    int carry = 0;
    for (int c = 0; c < NB; c += BLK) {
        int idx = c + t;
        int val = (idx < NB) ? g_hist[v * NB + idx] : 0;
        s[t] = val; __syncthreads();
        for (int off = 1; off < BLK; off <<= 1) {
            int tmp = (t >= off) ? s[t - off] : 0;
            __syncthreads();
            s[t] += tmp;
            __syncthreads();
        }
        int excl = s[t] - val;
        int tot  = s[BLK - 1];
        if (idx < NB) g_hist[v * NB + idx] = carry + excl;
        carry += tot;
        __syncthreads();
    }
    if (t == 0) g_total[v] = carry;
}

__global__ void scan_buckets_kernel(const int* __restrict__ g_total, int* __restrict__ g_base) {
    __shared__ int s[BLK];
    const int t = threadIdx.x;
    int carry = 0;
    for (int c = 0; c < NIMG_; c += BLK) {
        int idx = c + t;
        int val = (idx < NIMG_) ? g_total[idx] : 0;
        s[t] = val; __syncthreads();
        for (int off = 1; off < BLK; off <<= 1) {
            int tmp = (t >= off) ? s[t - off] : 0;
            __syncthreads();
            s[t] += tmp;
            __syncthreads();
        }
        if (idx < NIMG_) g_base[idx] = carry + (s[t] - val);
        carry += s[BLK - 1];
        __syncthreads();
    }
}

__global__ void rank_kernel(const int* __restrict__ img, const int* __restrict__ g_hist,
                            const int* __restrict__ g_base, int* __restrict__ rank) {
    __shared__ int simg[BLK];
    const int t = threadIdx.x, b = blockIdx.x;
    int a = b * BLK + t;
    int v = (a < QTOT) ? img[a] : -1;
    simg[t] = v;
    __syncthreads();
    if (a < QTOT) {
        int local = 0;
        for (int j = 0; j < t; ++j) {
            if (simg[j] == v) local++;
        }
        rank[a] = g_base[v] + g_hist[v * NB + b] + local;
    }
}

// ---------------- per-atom MLP forward + backward ---------------------------
__global__ __launch_bounds__(BLK) void mlp_kernel(
    const float* __restrict__ fps, const float* __restrict__ W1, const float* __restrict__ b1,
    const float* __restrict__ W2, const float* __restrict__ b2, const float* __restrict__ W3,
    const float* __restrict__ b3, const int* __restrict__ img, const int* __restrict__ rank,
    float* __restrict__ energy, float* __restrict__ dEflat)
{
    __shared__ float sW1[P_ * H_], sW2[H_ * H_], sW3[H_], sB1[H_], sB2[H_];
    __shared__ float sB3;
    const int e = blockIdx.y;
    const int t = threadIdx.x;
    for (int i = t; i < P_ * H_; i += BLK) sW1[i] = W1[e * P_ * H_ + i];
    for (int i = t; i < H_ * H_; i += BLK) sW2[i] = W2[e * H_ * H_ + i];
    if (t < H_) { sW3[t] = W3[e * H_ + t]; sB1[t] = b1[e * H_ + t]; sB2[t] = b2[e * H_ + t]; }
    if (t == 0) sB3 = b3[e];
    __syncthreads();

    int q = blockIdx.x * BLK + t;
    if (q >= QE_) return;
    int a = e * QE_ + q;

    const vf4* xp = (const vf4*)(fps + (size_t)a * P_);
    float x[P_];
    #pragma unroll
    for (int p = 0; p < P_; p += 4) {
        vf4 v4 = __builtin_nontemporal_load(xp + (p >> 2));
        x[p] = v4.x; x[p+1] = v4.y; x[p+2] = v4.z; x[p+3] = v4.w;
    }

    float h1v[H_], h2v[H_];
    #pragma unroll
    for (int i = 0; i < H_; ++i) {
        float z = sB1[i];
        #pragma unroll
        for (int p = 0; p < P_; ++p) z += x[p] * sW1[p * H_ + i];
        h1v[i] = tanhf(z);
    }
    #pragma unroll
    for (int i = 0; i < H_; ++i) {
        float z = sB2[i];
        #pragma unroll
        for (int j = 0; j < H_; ++j) z += h1v[j] * sW2[j * H_ + i];
        h2v[i] = tanhf(z);
    }
    float ea = sB3;
    #pragma unroll
    for (int i = 0; i < H_; ++i) ea += h2v[i] * sW3[i];
    atomicAdd(&energy[img[a]], ea);

    float dz2[H_];
    #pragma unroll
    for (int i = 0; i < H_; ++i) dz2[i] = sW3[i] * (1.0f - h2v[i] * h2v[i]);
    float dz1[H_];
    #pragma unroll
    for (int i = 0; i < H_; ++i) {
        float d = 0.0f;
        #pragma unroll
        for (int j = 0; j < H_; ++j) d += sW2[i * H_ + j] * dz2[j];
        dz1[i] = d * (1.0f - h1v[i] * h1v[i]);
    }
    float* op = dEflat + (size_t)rank[a] * P_;
    #pragma unroll
    for (int p = 0; p < P_; p += 4) {
        float4 v4;
        float d0 = 0.f, d1 = 0.f, d2 = 0.f, d3 = 0.f;
        #pragma unroll
        for (int i = 0; i < H_; ++i) {
            d0 += sW1[(p    ) * H_ + i] * dz1[i];
            d1 += sW1[(p + 1) * H_ + i] * dz1[i];
            d2 += sW1[(p + 2) * H_ + i] * dz1[i];
            d3 += sW1[(p + 3) * H_ + i] * dz1[i];
        }
        v4.x = d0; v4.y = d1; v4.z = d2; v4.w = d3;
        *(float4*)(op + p) = v4;   // cacheable: re-read by fscatter gather
    }
}

// ============ v4 front end: capacity-reservation slice grouping =============

// slice_scatter: one streaming pass; group nnz by row-slice via per-block
// LDS hist + ONE global cursor atomicAdd per (block,slice).
// item = { (val15<<17)|rowLocal17 , col }
__global__ __launch_bounds__(BLK) void slice_scatter_kernel(
    const int* __restrict__ rows, const int* __restrict__ cols, const float* __restrict__ vals,
    int* __restrict__ ctrl, uint2* __restrict__ items)
{
    __shared__ uint32 srow[SC];          // 32 KB staged rows
    __shared__ int h[NSLICE], lcur[NSLICE], gbase[NSLICE];
    const int t = threadIdx.x, b = blockIdx.x;
    const int base = b * SC;
    const int len = min(SC, NNZ_ - base);
    const bool full = (len == SC);

    if (t < NSLICE) h[t] = 0;
    __syncthreads();
    if (full) {
        const vi4* r4 = (const vi4*)(rows + base);
        #pragma unroll
        for (int j = 0; j < SC / (BLK * 4); ++j) {
            int idx = j * BLK + t;
            vi4 rr = __builtin_nontemporal_load(r4 + idx);
            srow[idx * 4 + 0] = (uint32)rr.x; atomicAdd(&h[rr.x >> SLICE_SHIFT], 1);
            srow[idx * 4 + 1] = (uint32)rr.y; atomicAdd(&h[rr.y >> SLICE_SHIFT], 1);
            srow[idx * 4 + 2] = (uint32)rr.z; atomicAdd(&h[rr.z >> SLICE_SHIFT], 1);
            srow[idx * 4 + 3] = (uint32)rr.w; atomicAdd(&h[rr.w >> SLICE_SHIFT], 1);
        }
    } else {
        for (int j = t; j < len; j += BLK) {
            int r = rows[base + j];
            srow[j] = (uint32)r;
            atomicAdd(&h[r >> SLICE_SHIFT], 1);
        }
    }
    __syncthreads();
    if (t < NSLICE) {
        lcur[t] = 0;
        gbase[t] = (h[t] > 0) ? atomicAdd(&ctrl[C_SCUR + t], h[t]) : 0;
    }
    __syncthreads();
    if (full) {
        const vi4* c4 = (const vi4*)(cols + base);
        const vi4* v4 = (const vf4*)(vals + base) ? (const vi4*)(vals + base) : nullptr;
        #pragma unroll 2
        for (int j = 0; j < SC / (BLK * 4); ++j) {
            int idx = j * BLK + t;
            vi4 cc = __builtin_nontemporal_load(c4 + idx);
            vi4 vv = __builtin_nontemporal_load(v4 + idx);
            #define EMIT(K, CI, VB)                                                \
            {                                                                      \
                uint32 r = srow[idx * 4 + K];                                      \
                int sl = (int)(r >> SLICE_SHIFT);                                  \
                int pos = gbase[sl] + atomicAdd(&lcur[sl], 1);                     \
                uint32 v15 = (((uint32)(VB)) + 0x10000u) >> 17;                    \
                items[(size_t)sl * CAPS + pos] =                                   \
                    make_uint2((v15 << 17) | (r & 0x1FFFFu), (uint32)(CI));        \
            }
            EMIT(0, cc.x, vv.x)
            EMIT(1, cc.y, vv.y)
            EMIT(2, cc.z, vv.z)
            EMIT(3, cc.w, vv.w)
        }
    } else {
        for (int j = t; j < len; j += BLK) {
            uint32 r = srow[j];
            int sl = (int)(r >> SLICE_SHIFT);
            int pos = gbase[sl] + atomicAdd(&lcur[sl], 1);
            uint32 vb = ((const uint32*)vals)[base + j];
            uint32 v15 = (vb + 0x10000u) >> 17;
            items[(size_t)sl * CAPS + pos] =
                make_uint2((v15 << 17) | (r & 0x1FFFFu), (uint32)cols[base + j]);
        }
    }
}

// plan4: slice counts -> chunk tables + XCD group lists.
__global__ void plan4_kernel(int* __restrict__ ctrl) {
    __shared__ int scnt[NSLICE], cb[NSLICE + 1], gp[NSLICE];
    __shared__ int g8[8], tot_s;
    const int t = threadIdx.x;
    if (t < NSLICE) scnt[t] = ctrl[C_SCUR + t];
    __syncthreads();
    if (t == 0) {
        int crun = 0;
        int gs[8]; for (int x = 0; x < 8; ++x) gs[x] = 0;
        for (int s = 0; s < NSLICE; ++s) {
            int nc = (scnt[s] + SC - 1) / SC;
            cb[s] = crun; crun += nc;
            int x = s & 7;
            gp[s] = gs[x]; gs[x] += nc;
        }
        cb[NSLICE] = crun; tot_s = crun;
        for (int x = 0; x < 8; ++x) g8[x] = gs[x];
    }
    __syncthreads();
    const int tot = tot_s;
    if (t < 8) ctrl[C_GCNT + t] = g8[t];
    for (int idx = t; idx < tot; idx += BLK) {
        int s = 0;
        for (int k = 0; k < NSLICE; ++k) if (cb[k] <= idx) s = k;
        int c = idx - cb[s];
        ctrl[C_CHS + idx]   = s;
        ctrl[C_CHST + idx]  = s * CAPS + c * SC;
        ctrl[C_CHLEN + idx] = min(SC, scnt[s] - c * SC);
        ctrl[C_GRP + (s & 7) * 256 + gp[s] + c] = idx;
    }
}

// fscatter5: XCD-pinned chunks; L2-local dE gather, fused multiply, DIRECT
// f32 atomicAdd into this XCD's private force replica (2.16 MB, L2-resident).
// No histogram, no scan, no LDS sort, no bm, no barriers.
__global__ __launch_bounds__(BLK) void fscatter5_kernel(
    const uint2* __restrict__ items, const float* __restrict__ dEflat,
    const int* __restrict__ ctrl, float* __restrict__ frep)
{
    const int t = threadIdx.x;
    const int x = blockIdx.x & 7;         // assumed XCD (round-robin dispatch)
    const int r = blockIdx.x >> 3;
    const int gc = ctrl[C_GCNT + x];
    float* __restrict__ fx = frep + (size_t)x * FSZ;

    for (int w = r; w < gc; w += FS_PERX2) {
        const int g     = ctrl[C_GRP + x * 256 + w];
        const int sl    = ctrl[C_CHS + g];
        const int start = ctrl[C_CHST + g];
        const int len   = ctrl[C_CHLEN + g];
        const float* __restrict__ dE = dEflat + ((size_t)sl << SLICE_SHIFT);

        if (len == SC) {
            const vi4* p4 = (const vi4*)(items + start);
            #pragma unroll 4
            for (int j = 0; j < SC / (BLK * 2); ++j) {
                vi4 q = __builtin_nontemporal_load(p4 + j * BLK + t);
                float dA = dE[((uint32)q.x) & 0x1FFFFu];
                float dB = dE[((uint32)q.z) & 0x1FFFFu];
                float vA = __uint_as_float((((uint32)q.x) >> 17) << 17);
                float vB = __uint_as_float((((uint32)q.z) >> 17) << 17);
                atomicAdd(&fx[(uint32)q.y], -vA * dA);
                atomicAdd(&fx[(uint32)q.w], -vB * dB);
            }
        } else {
            for (int j = t; j < len; j += BLK) {
                uint2 it = items[start + j];
                float d = dE[it.x & 0x1FFFFu];
                float v = __uint_as_float((it.x >> 17) << 17);
                atomicAdd(&fx[it.y], -v * d);
            }
        }
    }
}

// freduce5: sum the 8 XCD replicas into the force output.
__global__ void freduce5_kernel(const float* __restrict__ frep,
                                float* __restrict__ force) {
    int i = blockIdx.x * BLK + threadIdx.x;
    if (i < FSZ) {
        float s = 0.0f;
        #pragma unroll
        for (int k = 0; k < NREP; ++k)
            s += __builtin_nontemporal_load(frep + (size_t)k * FSZ + i);
        force[i] = s;
    }
}

// ================= R5 fallback path (unsliced) ==============================
__global__ __launch_bounds__(BLK) void fhist_kernel(const int* __restrict__ cols,
                                                    int* __restrict__ binHist) {
    __shared__ int h[NBIN];
    const int t = threadIdx.x, b = blockIdx.x;
    if (t < NBIN) h[t] = 0;
    __syncthreads();
    const int base = b * SC;
    if (base + SC <= NNZ_) {
        const vi4* c4 = (const vi4*)(cols + base);
        #pragma unroll
        for (int j = 0; j < SC / (BLK * 4); ++j) {
            vi4 cc = __builtin_nontemporal_load(c4 + j * BLK + t);
            atomicAdd(&h[cc.x >> CW_BITS], 1);
            atomicAdd(&h[cc.y >> CW_BITS], 1);
            atomicAdd(&h[cc.z >> CW_BITS], 1);
            atomicAdd(&h[cc.w >> CW_BITS], 1);
        }
    } else {
        for (int j = 0; j < SC / BLK; ++j) {
            int k = base + j * BLK + t;
            if (k < NNZ_) atomicAdd(&h[cols[k] >> CW_BITS], 1);
        }
    }
    __syncthreads();
    if (t < NBIN) binHist[t * NSB + b] = h[t];
}

__global__ void fscan_blocks_kernel(int* __restrict__ binHist, int* __restrict__ binTotal,
                                    int n) {
    __shared__ int s[BLK];
    const int v = blockIdx.x, t = threadIdx.x;
    int carry = 0;
    for (int c = 0; c < n; c += BLK) {
        int idx = c + t;
        int val = (idx < n) ? binHist[v * n + idx] : 0;
        s[t] = val; __syncthreads();
        for (int off = 1; off < BLK; off <<= 1) {
            int tmp = (t >= off) ? s[t - off] : 0;
            __syncthreads();
            s[t] += tmp;
            __syncthreads();
        }
        int excl = s[t] - val;
        int tot  = s[BLK - 1];
        if (idx < n) binHist[v * n + idx] = carry + excl;
        carry += tot;
        __syncthreads();
    }
    if (t == 0) binTotal[v] = carry;
}

__global__ void fbase_kernel(const int* __restrict__ binTotal, int* __restrict__ binBase) {
    __shared__ int s[BLK];
    const int t = threadIdx.x;
    int v = (t < NBIN) ? binTotal[t] : 0;
    s[t] = v; __syncthreads();
    for (int off = 1; off < BLK; off <<= 1) {
        int tmp = (t >= off) ? s[t - off] : 0;
        __syncthreads();
        s[t] += tmp;
        __syncthreads();
    }
    if (t < NBIN) binBase[t] = s[t] - v;
    if (t == 0) binBase[NBIN] = s[BLK - 1];
}

__global__ __launch_bounds__(BLK) void fscatter_kernel(
    const int* __restrict__ rows, const int* __restrict__ cols, const float* __restrict__ vals,
    const float* __restrict__ dEflat, const int* __restrict__ binHist,
    const int* __restrict__ binBase, uint32* __restrict__ bm)
{
    __shared__ uint32 items[SC];
    __shared__ unsigned char bins[SC];
    __shared__ int hist[NBIN];
    __shared__ int cursor[NBIN];
    __shared__ int delta[NBIN];
    __shared__ int s[BLK];
    const int t = threadIdx.x, b = blockIdx.x;
    const int base = b * SC;
    const int nIt = min(SC, NNZ_ - base);
    const bool full = (base + SC <= NNZ_);

    if (t < NBIN) hist[t] = 0;
    __syncthreads();
    if (full) {
        const vi4* c4 = (const vi4*)(cols + base);
        #pragma unroll
        for (int j = 0; j < SC / (BLK * 4); ++j) {
            vi4 cc = __builtin_nontemporal_load(c4 + j * BLK + t);
            atomicAdd(&hist[cc.x >> CW_BITS], 1);
            atomicAdd(&hist[cc.y >> CW_BITS], 1);
            atomicAdd(&hist[cc.z >> CW_BITS], 1);
            atomicAdd(&hist[cc.w >> CW_BITS], 1);
        }
    } else {
        for (int j = 0; j < SC / BLK; ++j) {
            int k = base + j * BLK + t;
            if (k < NNZ_) atomicAdd(&hist[cols[k] >> CW_BITS], 1);
        }
    }
    __syncthreads();
    {
        int v = (t < NBIN) ? hist[t] : 0;
        s[t] = v; __syncthreads();
        for (int off = 1; off < BLK; off <<= 1) {
            int tmp = (t >= off) ? s[t - off] : 0;
            __syncthreads();
            s[t] += tmp;
            __syncthreads();
        }
        if (t < NBIN) {
            int ls = s[t] - v;
            cursor[t] = ls;
            delta[t]  = binBase[t] + binHist[t * NSB + b] - ls;
        }
    }
    __syncthreads();
    if (full) {
        const vi4* c4 = (const vi4*)(cols + base);
        const vi4* r4 = (const vi4*)(rows + base);
        const vf4* v4 = (const vf4*)(vals + base);
        #pragma unroll 2
        for (int j = 0; j < SC / (BLK * 4); ++j) {
            int idx = j * BLK + t;
            vi4 cc = __builtin_nontemporal_load(c4 + idx);
            vi4 rr = __builtin_nontemporal_load(r4 + idx);
            vf4 vv = __builtin_nontemporal_load(v4 + idx);
            float d0 = dEflat[rr.x];
            float d1 = dEflat[rr.y];
            float d2 = dEflat[rr.z];
            float d3 = dEflat[rr.w];
            #define PLACE(CI, VI, DI)                                              \
            {                                                                      \
                int bin = (CI) >> CW_BITS;                                         \
                uint32 u = __float_as_uint(-(VI) * (DI));                          \
                uint32 pk = ((uint32)((CI) & (CW - 1)) << 20)                      \
                            | ((u + 0x800u) >> 12);                                \
                int pos = atomicAdd(&cursor[bin], 1);                              \
                items[pos] = pk;                                                   \
                bins[pos] = (unsigned char)bin;                                    \
            }
            PLACE(cc.x, vv.x, d0)
            PLACE(cc.y, vv.y, d1)
            PLACE(cc.z, vv.z, d2)
            PLACE(cc.w, vv.w, d3)
        }
    } else {
        for (int j = 0; j < SC / BLK; ++j) {
            int k = base + j * BLK + t;
            if (k < NNZ_) {
                int c = cols[k];
                float d = dEflat[rows[k]];
                float v = vals[k];
                PLACE(c, v, d)
            }
        }
    }
    __syncthreads();
    for (int i = t; i < nIt; i += BLK) {
        __builtin_nontemporal_store(items[i], &bm[delta[bins[i]] + i]);
    }
}

__global__ __launch_bounds__(BLK) void fforce_kernel(
    const uint32* __restrict__ bm, const int* __restrict__ binBase,
    float* __restrict__ partial)
{
    __shared__ float w[CW];
    const int t = threadIdx.x;
    const int bin = blockIdx.x >> 3;
    const int sub = blockIdx.x & (SUBS - 1);
    for (int i = t; i < CW; i += BLK) w[i] = 0.0f;
    __syncthreads();
    const int start = binBase[bin];
    const int cnt   = binBase[bin + 1] - start;
    const int sBeg  = start + (cnt * sub) / SUBS;
    const int sEnd  = start + (cnt * (sub + 1)) / SUBS;
    int i = sBeg + t;
    for (; i + 3 * BLK < sEnd; i += 4 * BLK) {
        uint32 p0 = __builtin_nontemporal_load(bm + i);
        uint32 p1 = __builtin_nontemporal_load(bm + i + BLK);
        uint32 p2 = __builtin_nontemporal_load(bm + i + 2 * BLK);
        uint32 p3 = __builtin_nontemporal_load(bm + i + 3 * BLK);
        atomicAdd(&w[p0 >> 20], __uint_as_float((p0 & 0xFFFFFu) << 12));
        atomicAdd(&w[p1 >> 20], __uint_as_float((p1 & 0xFFFFFu) << 12));
        atomicAdd(&w[p2 >> 20], __uint_as_float((p2 & 0xFFFFFu) << 12));
        atomicAdd(&w[p3 >> 20], __uint_as_float((p3 & 0xFFFFFu) << 12));
    }
    for (; i < sEnd; i += BLK) {
        uint32 p = bm[i];
        atomicAdd(&w[p >> 20], __uint_as_float((p & 0xFFFFFu) << 12));
    }
    __syncthreads();
    float* dst = partial + (size_t)blockIdx.x * CW;
    for (int k = t; k < CW; k += BLK) __builtin_nontemporal_store(w[k], dst + k);
}

__global__ void freduce_kernel(const float* __restrict__ partial, float* __restrict__ force) {
    int i = blockIdx.x * BLK + threadIdx.x;
    if (i < 3 * QTOT) {
        int bin = i >> CW_BITS, local = i & (CW - 1);
        const float* p = partial + (size_t)bin * (CW * SUBS) + local;
        float sum = 0.0f;
        #pragma unroll
        for (int k = 0; k < SUBS; ++k) sum += __builtin_nontemporal_load(p + k * CW);
        force[i] = sum;
    }
}

__global__ void force_kernel(const int* __restrict__ rows, const int* __restrict__ cols,
                             const float* __restrict__ vals, const float* __restrict__ dEflat,
                             float* __restrict__ force) {
    int k = blockIdx.x * blockDim.x + threadIdx.x;
    if (k < NNZ_) {
        float contrib = -vals[k] * dEflat[rows[k]];
        atomicAdd(&force[cols[k]], contrib);
    }
}

extern "C" void kernel_launch(void* const* d_in, const int* in_sizes, int n_in,
                              void* d_out, int out_size, void* d_ws, size_t ws_size,
                              hipStream_t stream) {
    (void)in_sizes; (void)n_in; (void)out_size;
    const float* fps  = (const float*)d_in[0];
    const float* W1   = (const float*)d_in[1];
    const float* b1   = (const float*)d_in[2];
    const float* W2   = (const float*)d_in[3];
    const float* b2   = (const float*)d_in[4];
    const float* W3   = (const float*)d_in[5];
    const float* b3   = (const float*)d_in[6];
    const int*   img  = (const int*)d_in[7];
    const int*   rows = (const int*)d_in[8];
    const int*   cols = (const int*)d_in[9];
    const float* vals = (const float*)d_in[10];

    char* ws = (char*)d_ws;
    float* energy = (float*)d_out;                   // [1800]
    float* force  = (float*)d_out + NIMG_;           // [540000]
    const int nOut = NIMG_ + 3 * QTOT;

    // v5 layout:
    //   [0, 5.80 MB)      rank scratch  (dead after mlp)
    //   [0, 118.95 MB)    items uint2[55*CAPS]     (overlay; live after mlp)
    //   [118.95, 136.23)  frep float[8*540000]     (17.28 MB, per-XCD replicas)
    //   [179.50, 179.54)  ctrl
    //   [179.54, 208.34)  dEflat
    int*    g_hist  = (int*)(ws);
    int*    g_total = (int*)(ws + 5068800);
    int*    g_base  = (int*)(ws + 5076000);
    int*    rank    = (int*)(ws + 5083200);
    uint2*  items   = (uint2*)(ws);
    float*  frep    = (float*)(ws + 118947840);
    int*    ctrl    = (int*)(ws + 179503104);
    float*  dEflat4 = (float*)(ws + 179536384);
    const size_t WS_V4 = 208336384;

    // R5 fallback layout
    float*  dEflat5   = (float*)(ws + 5803200);
    int*    binHist5  = (int*)(ws + 34603200);
    int*    binTotal5 = (int*)(ws + 35531424);
    int*    binBase5  = (int*)(ws + 35531952);
    uint32* bm5       = (uint32*)(ws + 35532496);
    float*  partial5  = (float*)(ws + 93132496);
    const size_t WS_V2 = 110434000;

    const bool v4 = (ws_size >= WS_V4);
    float* dEflat = v4 ? dEflat4 : dEflat5;

    zero_kernel<<<(nOut + BLK - 1) / BLK, BLK, 0, stream>>>((float*)d_out, nOut);

    // atom rank (stable argsort of image_idx)
    hist_kernel<<<NB, BLK, 0, stream>>>(img, g_hist);
    scan_blocks_kernel<<<NIMG_, BLK, 0, stream>>>(g_hist, g_total);
    scan_buckets_kernel<<<1, BLK, 0, stream>>>(g_total, g_base);
    rank_kernel<<<NB, BLK, 0, stream>>>(img, g_hist, g_base, rank);

    // per-atom MLP fwd+bwd
    dim3 gm((QE_ + BLK - 1) / BLK, E_);
    mlp_kernel<<<gm, BLK, 0, stream>>>(fps, W1, b1, W2, b2, W3, b3, img, rank,
                                       energy, dEflat);

    if (v4) {
        zero_kernel<<<(NREP * FSZ + BLK - 1) / BLK, BLK, 0, stream>>>(frep, NREP * FSZ);
        zero_ctrl_kernel<<<1, 256, 0, stream>>>(ctrl);
        slice_scatter_kernel<<<NSB, BLK, 0, stream>>>(rows, cols, vals, ctrl, items);
        plan4_kernel<<<1, BLK, 0, stream>>>(ctrl);
        fscatter5_kernel<<<FS_GRID2, BLK, 0, stream>>>(items, dEflat, ctrl, frep);
        freduce5_kernel<<<(FSZ + BLK - 1) / BLK, BLK, 0, stream>>>(frep, force);
    } else if (ws_size >= WS_V2) {
        fhist_kernel<<<NSB, BLK, 0, stream>>>(cols, binHist5);
        fscan_blocks_kernel<<<NBIN, BLK, 0, stream>>>(binHist5, binTotal5, NSB);
        fbase_kernel<<<1, BLK, 0, stream>>>(binTotal5, binBase5);
        fscatter_kernel<<<NSB, BLK, 0, stream>>>(rows, cols, vals, dEflat,
                                                 binHist5, binBase5, bm5);
        fforce_kernel<<<NBIN * SUBS, BLK, 0, stream>>>(bm5, binBase5, partial5);
        freduce_kernel<<<(3 * QTOT + BLK - 1) / BLK, BLK, 0, stream>>>(partial5, force);
    } else {
        force_kernel<<<NNZ_ / BLK, BLK, 0, stream>>>(rows, cols, vals, dEflat, force);
    }
}

// Round 3
// 628.787 us; speedup vs baseline: 1.7301x; 1.7301x over previous
//
#include <hip/hip_runtime.h>
#include <math.h>

#define E_    3
#define QE_   60000
#define QTOT  180000      // E_*QE_
#define P_    40
#define H_    20
#define NIMG_ 1800
#define NNZ_  14400000
#define BLK   256
#define NB    704         // ceil(QTOT/BLK)

// column-window partition for the sparse force accumulation
#define CW_BITS 12
#define CW      4096                  // cols per window (16 KB LDS accumulator)
#define NBIN    132                   // ceil(3*QTOT / CW)
#define SUBS    8                     // sub-slices per bin in force kernel
#define SC      8192                  // nnz items per chunk (input staging / fallback)
#define NSB     1758                  // ceil(NNZ_/SC)  (input chunking)

// row-slice partition: 131072 dE rows = 512 KB per slice -> fits XCD L2
#define SLICE_SHIFT 17
#define NSLICE  55                    // ceil(7.2M / 131072)
#define CAPS    270336                // per-slice item capacity (33*SC, +16 sigma)
#define CAPB    114688                // per-bin bm capacity (+16 sigma)

// fscatter4 chunking: SCF=4096 -> 19.5 KB LDS -> ~7 blocks/CU (occupancy fix)
#define SCF     4096                  // items per fscatter4 chunk
#define NCHMAX  512                   // per-XCD-group chunk list capacity
#define FS_GRID 1792                  // 8 XCD groups x 224 blocks
#define FS_PERX 224                   // blocks per XCD group (7/CU x 32 CU)

// ctrl int offsets
#define C_SCUR  0      // [55]    slice cursors (= counts after slice_scatter)
#define C_BCUR  64     // [132]   bin cursors   (= counts after fscatter4)
#define C_GCNT  256    // [8]     per-XCD-group chunk counts
#define C_GRP   512    // [8*512] per-XCD-group packed chunk refs: (slice<<8)|c
#define C_INTS  4608

typedef int   vi4 __attribute__((ext_vector_type(4)));
typedef float vf4 __attribute__((ext_vector_type(4)));
typedef unsigned uint32;

// ---------------- zero init -------------------------------------------------
__global__ void zero_kernel(float* __restrict__ out, int n) {
    int i = blockIdx.x * blockDim.x + threadIdx.x;
    if (i < n) out[i] = 0.0f;
}
__global__ void zero_ctrl_kernel(int* __restrict__ ctrl) {
    ctrl[threadIdx.x] = 0;   // zeros C_SCUR + C_BCUR (first 256 ints)
}

// ---------------- stable counting sort for atom ranks ----------------------
__global__ void hist_kernel(const int* __restrict__ img, int* __restrict__ g_hist) {
    __shared__ int h[NIMG_];
    const int t = threadIdx.x, b = blockIdx.x;
    for (int v = t; v < NIMG_; v += BLK) h[v] = 0;
    __syncthreads();
    int a = b * BLK + t;
    if (a < QTOT) atomicAdd(&h[img[a]], 1);
    __syncthreads();
    for (int v = t; v < NIMG_; v += BLK) g_hist[v * NB + b] = h[v];
}

__global__ void scan_blocks_kernel(int* __restrict__ g_hist, int* __restrict__ g_total) {
    __shared__ int s[BLK];
    const int v = blockIdx.x, t = threadIdx.x;
    int carry = 0;
    for (int c = 0; c < NB; c += BLK) {
        int idx = c + t;
        int val = (idx < NB) ? g_hist[v * NB + idx] : 0;
        s[t] = val; __syncthreads();
        for (int off = 1; off < BLK; off <<= 1) {
            int tmp = (t >= off) ? s[t - off] : 0;
            __syncthreads();
            s[t] += tmp;
            __syncthreads();
        }
        int excl = s[t] - val;
        int tot  = s[BLK - 1];
        if (idx < NB) g_hist[v * NB + idx] = carry + excl;
        carry += tot;
        __syncthreads();
    }
    if (t == 0) g_total[v] = carry;
}

__global__ void scan_buckets_kernel(const int* __restrict__ g_total, int* __restrict__ g_base) {
    __shared__ int s[BLK];
    const int t = threadIdx.x;
    int carry = 0;
    for (int c = 0; c < NIMG_; c += BLK) {
        int idx = c + t;
        int val = (idx < NIMG_) ? g_total[idx] : 0;
        s[t] = val; __syncthreads();
        for (int off = 1; off < BLK; off <<= 1) {
            int tmp = (t >= off) ? s[t - off] : 0;
            __syncthreads();
            s[t] += tmp;
            __syncthreads();
        }
        if (idx < NIMG_) g_base[idx] = carry + (s[t] - val);
        carry += s[BLK - 1];
        __syncthreads();
    }
}

__global__ void rank_kernel(const int* __restrict__ img, const int* __restrict__ g_hist,
                            const int* __restrict__ g_base, int* __restrict__ rank) {
    __shared__ int simg[BLK];
    const int t = threadIdx.x, b = blockIdx.x;
    int a = b * BLK + t;
    int v = (a < QTOT) ? img[a] : -1;
    simg[t] = v;
    __syncthreads();
    if (a < QTOT) {
        int local = 0;
        for (int j = 0; j < t; ++j) {
            if (simg[j] == v) local++;
        }
        rank[a] = g_base[v] + g_hist[v * NB + b] + local;
    }
}

// ---------------- per-atom MLP forward + backward ---------------------------
__global__ __launch_bounds__(BLK) void mlp_kernel(
    const float* __restrict__ fps, const float* __restrict__ W1, const float* __restrict__ b1,
    const float* __restrict__ W2, const float* __restrict__ b2, const float* __restrict__ W3,
    const float* __restrict__ b3, const int* __restrict__ img, const int* __restrict__ rank,
    float* __restrict__ energy, float* __restrict__ dEflat)
{
    __shared__ float sW1[P_ * H_], sW2[H_ * H_], sW3[H_], sB1[H_], sB2[H_];
    __shared__ float sB3;
    const int e = blockIdx.y;
    const int t = threadIdx.x;
    for (int i = t; i < P_ * H_; i += BLK) sW1[i] = W1[e * P_ * H_ + i];
    for (int i = t; i < H_ * H_; i += BLK) sW2[i] = W2[e * H_ * H_ + i];
    if (t < H_) { sW3[t] = W3[e * H_ + t]; sB1[t] = b1[e * H_ + t]; sB2[t] = b2[e * H_ + t]; }
    if (t == 0) sB3 = b3[e];
    __syncthreads();

    int q = blockIdx.x * BLK + t;
    if (q >= QE_) return;
    int a = e * QE_ + q;

    const vf4* xp = (const vf4*)(fps + (size_t)a * P_);
    float x[P_];
    #pragma unroll
    for (int p = 0; p < P_; p += 4) {
        vf4 v4 = __builtin_nontemporal_load(xp + (p >> 2));
        x[p] = v4.x; x[p+1] = v4.y; x[p+2] = v4.z; x[p+3] = v4.w;
    }

    float h1v[H_], h2v[H_];
    #pragma unroll
    for (int i = 0; i < H_; ++i) {
        float z = sB1[i];
        #pragma unroll
        for (int p = 0; p < P_; ++p) z += x[p] * sW1[p * H_ + i];
        h1v[i] = tanhf(z);
    }
    #pragma unroll
    for (int i = 0; i < H_; ++i) {
        float z = sB2[i];
        #pragma unroll
        for (int j = 0; j < H_; ++j) z += h1v[j] * sW2[j * H_ + i];
        h2v[i] = tanhf(z);
    }
    float ea = sB3;
    #pragma unroll
    for (int i = 0; i < H_; ++i) ea += h2v[i] * sW3[i];
    atomicAdd(&energy[img[a]], ea);

    float dz2[H_];
    #pragma unroll
    for (int i = 0; i < H_; ++i) dz2[i] = sW3[i] * (1.0f - h2v[i] * h2v[i]);
    float dz1[H_];
    #pragma unroll
    for (int i = 0; i < H_; ++i) {
        float d = 0.0f;
        #pragma unroll
        for (int j = 0; j < H_; ++j) d += sW2[i * H_ + j] * dz2[j];
        dz1[i] = d * (1.0f - h1v[i] * h1v[i]);
    }
    float* op = dEflat + (size_t)rank[a] * P_;
    #pragma unroll
    for (int p = 0; p < P_; p += 4) {
        float4 v4;
        float d0 = 0.f, d1 = 0.f, d2 = 0.f, d3 = 0.f;
        #pragma unroll
        for (int i = 0; i < H_; ++i) {
            d0 += sW1[(p    ) * H_ + i] * dz1[i];
            d1 += sW1[(p + 1) * H_ + i] * dz1[i];
            d2 += sW1[(p + 2) * H_ + i] * dz1[i];
            d3 += sW1[(p + 3) * H_ + i] * dz1[i];
        }
        v4.x = d0; v4.y = d1; v4.z = d2; v4.w = d3;
        *(float4*)(op + p) = v4;   // cacheable: re-read by fscatter gather
    }
}

// ============ v4: capacity-reservation slice grouping + pinned gather =======

// slice_scatter: one streaming pass; group nnz by row-slice via per-block
// LDS hist + ONE global cursor atomicAdd per (block,slice).
// item = { (val15<<17)|rowLocal17 , col }
__global__ __launch_bounds__(BLK) void slice_scatter_kernel(
    const int* __restrict__ rows, const int* __restrict__ cols, const float* __restrict__ vals,
    int* __restrict__ ctrl, uint2* __restrict__ items)
{
    __shared__ uint32 srow[SC];          // 32 KB staged rows
    __shared__ int h[NSLICE], lcur[NSLICE], gbase[NSLICE];
    const int t = threadIdx.x, b = blockIdx.x;
    const int base = b * SC;
    const int len = min(SC, NNZ_ - base);
    const bool full = (len == SC);

    if (t < NSLICE) h[t] = 0;
    __syncthreads();
    if (full) {
        const vi4* r4 = (const vi4*)(rows + base);
        #pragma unroll
        for (int j = 0; j < SC / (BLK * 4); ++j) {
            int idx = j * BLK + t;
            vi4 rr = __builtin_nontemporal_load(r4 + idx);
            srow[idx * 4 + 0] = (uint32)rr.x; atomicAdd(&h[rr.x >> SLICE_SHIFT], 1);
            srow[idx * 4 + 1] = (uint32)rr.y; atomicAdd(&h[rr.y >> SLICE_SHIFT], 1);
            srow[idx * 4 + 2] = (uint32)rr.z; atomicAdd(&h[rr.z >> SLICE_SHIFT], 1);
            srow[idx * 4 + 3] = (uint32)rr.w; atomicAdd(&h[rr.w >> SLICE_SHIFT], 1);
        }
    } else {
        for (int j = t; j < len; j += BLK) {
            int r = rows[base + j];
            srow[j] = (uint32)r;
            atomicAdd(&h[r >> SLICE_SHIFT], 1);
        }
    }
    __syncthreads();
    if (t < NSLICE) {
        lcur[t] = 0;
        gbase[t] = (h[t] > 0) ? atomicAdd(&ctrl[C_SCUR + t], h[t]) : 0;
    }
    __syncthreads();
    if (full) {
        const vi4* c4 = (const vi4*)(cols + base);
        const vi4* v4 = (const vi4*)(vals + base);
        #pragma unroll 2
        for (int j = 0; j < SC / (BLK * 4); ++j) {
            int idx = j * BLK + t;
            vi4 cc = __builtin_nontemporal_load(c4 + idx);
            vi4 vv = __builtin_nontemporal_load(v4 + idx);
            #define EMIT(K, CI, VB)                                                \
            {                                                                      \
                uint32 r = srow[idx * 4 + K];                                      \
                int sl = (int)(r >> SLICE_SHIFT);                                  \
                int pos = gbase[sl] + atomicAdd(&lcur[sl], 1);                     \
                uint32 v15 = (((uint32)(VB)) + 0x10000u) >> 17;                    \
                items[(size_t)sl * CAPS + pos] =                                   \
                    make_uint2((v15 << 17) | (r & 0x1FFFFu), (uint32)(CI));        \
            }
            EMIT(0, cc.x, vv.x)
            EMIT(1, cc.y, vv.y)
            EMIT(2, cc.z, vv.z)
            EMIT(3, cc.w, vv.w)
        }
    } else {
        for (int j = t; j < len; j += BLK) {
            uint32 r = srow[j];
            int sl = (int)(r >> SLICE_SHIFT);
            int pos = gbase[sl] + atomicAdd(&lcur[sl], 1);
            uint32 vb = ((const uint32*)vals)[base + j];
            uint32 v15 = (vb + 0x10000u) >> 17;
            items[(size_t)sl * CAPS + pos] =
                make_uint2((v15 << 17) | (r & 0x1FFFFu), (uint32)cols[base + j]);
        }
    }
}

// plan4: slice counts -> packed per-XCD-group chunk lists. Chunk ref packs
// (slice<<8)|chunkIdx; start/len are derived in fscatter4 from C_SCUR.
__global__ void plan4_kernel(int* __restrict__ ctrl) {
    __shared__ int scnt[NSLICE], cb[NSLICE + 1], gp[NSLICE];
    __shared__ int g8[8], tot_s;
    const int t = threadIdx.x;
    if (t < NSLICE) scnt[t] = ctrl[C_SCUR + t];
    __syncthreads();
    if (t == 0) {
        int crun = 0;
        int gs[8]; for (int x = 0; x < 8; ++x) gs[x] = 0;
        for (int s = 0; s < NSLICE; ++s) {
            int nc = (scnt[s] + SCF - 1) / SCF;
            cb[s] = crun; crun += nc;
            int x = s & 7;
            gp[s] = gs[x]; gs[x] += nc;
        }
        cb[NSLICE] = crun; tot_s = crun;
        for (int x = 0; x < 8; ++x) g8[x] = gs[x];
    }
    __syncthreads();
    const int tot = tot_s;
    if (t < 8) ctrl[C_GCNT + t] = g8[t];
    for (int idx = t; idx < tot; idx += BLK) {
        int s = 0;
        for (int k = 0; k < NSLICE; ++k) if (cb[k] <= idx) s = k;
        int c = idx - cb[s];
        ctrl[C_GRP + (s & 7) * NCHMAX + gp[s] + c] = (s << 8) | c;
    }
}

// fscatter4: XCD-pinned chunks; L2-local gather, fused multiply, block-local
// col sort, capacity-reserved coalesced write-out.
// v6: SCF=4096 + no bns[] (bins are contiguous itl segments; write-out is
// wave-per-bin segment copy) -> 19.5 KB LDS -> ~7 blocks/CU (was 3).
__global__ __launch_bounds__(BLK) void fscatter4_kernel(
    const uint2* __restrict__ items, const float* __restrict__ dEflat,
    int* __restrict__ ctrl, uint32* __restrict__ bm)
{
    __shared__ uint32 itl[SCF];           // 16 KB
    __shared__ int h[NBIN], cur[NBIN], ls[NBIN], dlt[NBIN];
    __shared__ int sc[BLK];
    const int t = threadIdx.x;
    const int x = blockIdx.x & 7;         // assumed XCD (round-robin dispatch)
    const int r = blockIdx.x >> 3;
    const int gc = ctrl[C_GCNT + x];

    for (int w = r; w < gc; w += FS_PERX) {
        const int pkd   = ctrl[C_GRP + x * NCHMAX + w];
        const int sl    = pkd >> 8;
        const int c     = pkd & 255;
        const int start = sl * CAPS + c * SCF;
        const int len   = min(SCF, ctrl[C_SCUR + sl] - c * SCF);
        const float* __restrict__ dE = dEflat + ((size_t)sl << SLICE_SHIFT);

        if (t < NBIN) h[t] = 0;
        __syncthreads();
        // pass 1: histogram over cols (items.y)
        if (len == SCF) {
            const vi4* p4 = (const vi4*)(items + start);
            #pragma unroll
            for (int j = 0; j < SCF / (BLK * 2); ++j) {
                vi4 q = __builtin_nontemporal_load(p4 + j * BLK + t);
                atomicAdd(&h[((uint32)q.y) >> CW_BITS], 1);
                atomicAdd(&h[((uint32)q.w) >> CW_BITS], 1);
            }
        } else {
            for (int j = t; j < len; j += BLK)
                atomicAdd(&h[items[start + j].y >> CW_BITS], 1);
        }
        __syncthreads();
        // local scan -> segment starts; global capacity reservation -> dlt
        {
            int v = (t < NBIN) ? h[t] : 0;
            sc[t] = v; __syncthreads();
            for (int off = 1; off < BLK; off <<= 1) {
                int tmp = (t >= off) ? sc[t - off] : 0;
                __syncthreads();
                sc[t] += tmp;
                __syncthreads();
            }
            if (t < NBIN) {
                int st = sc[t] - v;
                ls[t] = st;
                cur[t] = st;
                int gb = (v > 0) ? atomicAdd(&ctrl[C_BCUR + t], v) : 0;
                dlt[t] = t * CAPB + gb;
            }
        }
        __syncthreads();
        // pass 2: gather (L2-local) + fused multiply + local placement
        #define PLACE4(LO, CO, DI)                                             \
        {                                                                      \
            uint32 col = (uint32)(CO);                                         \
            int bin = (int)(col >> CW_BITS);                                   \
            float val = __uint_as_float((((uint32)(LO)) >> 17) << 17);         \
            uint32 u = __float_as_uint(-val * (DI));                           \
            uint32 pk = ((col & (CW - 1)) << 20) | ((u + 0x800u) >> 12);       \
            int pos = atomicAdd(&cur[bin], 1);                                 \
            itl[pos] = pk;                                                     \
        }
        if (len == SCF) {
            const vi4* p4 = (const vi4*)(items + start);
            #pragma unroll 4
            for (int j = 0; j < SCF / (BLK * 2); ++j) {
                vi4 q = __builtin_nontemporal_load(p4 + j * BLK + t);
                float dA = dE[((uint32)q.x) & 0x1FFFFu];
                float dB = dE[((uint32)q.z) & 0x1FFFFu];
                PLACE4(q.x, q.y, dA)
                PLACE4(q.z, q.w, dB)
            }
        } else {
            for (int j = t; j < len; j += BLK) {
                uint2 it = items[start + j];
                float d = dE[it.x & 0x1FFFFu];
                PLACE4(it.x, it.y, d)
            }
        }
        __syncthreads();
        // write-out: wave-per-bin contiguous segment copy (coalesced both sides)
        {
            const int wv = t >> 6, ln = t & 63;
            for (int b = wv; b < NBIN; b += 4) {
                int s0 = ls[b];
                int cnt = cur[b] - s0;
                int gb = dlt[b];
                for (int k = ln; k < cnt; k += 64)
                    __builtin_nontemporal_store(itl[s0 + k], &bm[gb + k]);
            }
        }
        __syncthreads();
    }
}

// fforce4: per (bin, sub-slice) LDS accumulation over capacity-based bm.
__global__ __launch_bounds__(BLK) void fforce4_kernel(
    const uint32* __restrict__ bm, const int* __restrict__ ctrl,
    float* __restrict__ partial)
{
    __shared__ float w[CW];
    const int t = threadIdx.x;
    const int bin = blockIdx.x >> 3;
    const int sub = blockIdx.x & (SUBS - 1);
    for (int i = t; i < CW; i += BLK) w[i] = 0.0f;
    __syncthreads();
    const int cnt   = ctrl[C_BCUR + bin];
    const int start = bin * CAPB;
    const int sBeg  = start + (cnt * sub) / SUBS;
    const int sEnd  = start + (cnt * (sub + 1)) / SUBS;
    int i = sBeg + t;
    for (; i + 3 * BLK < sEnd; i += 4 * BLK) {
        uint32 p0 = __builtin_nontemporal_load(bm + i);
        uint32 p1 = __builtin_nontemporal_load(bm + i + BLK);
        uint32 p2 = __builtin_nontemporal_load(bm + i + 2 * BLK);
        uint32 p3 = __builtin_nontemporal_load(bm + i + 3 * BLK);
        atomicAdd(&w[p0 >> 20], __uint_as_float((p0 & 0xFFFFFu) << 12));
        atomicAdd(&w[p1 >> 20], __uint_as_float((p1 & 0xFFFFFu) << 12));
        atomicAdd(&w[p2 >> 20], __uint_as_float((p2 & 0xFFFFFu) << 12));
        atomicAdd(&w[p3 >> 20], __uint_as_float((p3 & 0xFFFFFu) << 12));
    }
    for (; i < sEnd; i += BLK) {
        uint32 p = bm[i];
        atomicAdd(&w[p >> 20], __uint_as_float((p & 0xFFFFFu) << 12));
    }
    __syncthreads();
    float* dst = partial + (size_t)blockIdx.x * CW;
    for (int k = t; k < CW; k += BLK) __builtin_nontemporal_store(w[k], dst + k);
}

__global__ void freduce_kernel(const float* __restrict__ partial, float* __restrict__ force) {
    int i = blockIdx.x * BLK + threadIdx.x;
    if (i < 3 * QTOT) {
        int bin = i >> CW_BITS, local = i & (CW - 1);
        const float* p = partial + (size_t)bin * (CW * SUBS) + local;
        float sum = 0.0f;
        #pragma unroll
        for (int k = 0; k < SUBS; ++k) sum += __builtin_nontemporal_load(p + k * CW);
        force[i] = sum;
    }
}

// ================= R5 fallback path (unsliced) ==============================
__global__ __launch_bounds__(BLK) void fhist_kernel(const int* __restrict__ cols,
                                                    int* __restrict__ binHist) {
    __shared__ int h[NBIN];
    const int t = threadIdx.x, b = blockIdx.x;
    if (t < NBIN) h[t] = 0;
    __syncthreads();
    const int base = b * SC;
    if (base + SC <= NNZ_) {
        const vi4* c4 = (const vi4*)(cols + base);
        #pragma unroll
        for (int j = 0; j < SC / (BLK * 4); ++j) {
            vi4 cc = __builtin_nontemporal_load(c4 + j * BLK + t);
            atomicAdd(&h[cc.x >> CW_BITS], 1);
            atomicAdd(&h[cc.y >> CW_BITS], 1);
            atomicAdd(&h[cc.z >> CW_BITS], 1);
            atomicAdd(&h[cc.w >> CW_BITS], 1);
        }
    } else {
        for (int j = 0; j < SC / BLK; ++j) {
            int k = base + j * BLK + t;
            if (k < NNZ_) atomicAdd(&h[cols[k] >> CW_BITS], 1);
        }
    }
    __syncthreads();
    if (t < NBIN) binHist[t * NSB + b] = h[t];
}

__global__ void fscan_blocks_kernel(int* __restrict__ binHist, int* __restrict__ binTotal,
                                    int n) {
    __shared__ int s[BLK];
    const int v = blockIdx.x, t = threadIdx.x;
    int carry = 0;
    for (int c = 0; c < n; c += BLK) {
        int idx = c + t;
        int val = (idx < n) ? binHist[v * n + idx] : 0;
        s[t] = val; __syncthreads();
        for (int off = 1; off < BLK; off <<= 1) {
            int tmp = (t >= off) ? s[t - off] : 0;
            __syncthreads();
            s[t] += tmp;
            __syncthreads();
        }
        int excl = s[t] - val;
        int tot  = s[BLK - 1];
        if (idx < n) binHist[v * n + idx] = carry + excl;
        carry += tot;
        __syncthreads();
    }
    if (t == 0) binTotal[v] = carry;
}

__global__ void fbase_kernel(const int* __restrict__ binTotal, int* __restrict__ binBase) {
    __shared__ int s[BLK];
    const int t = threadIdx.x;
    int v = (t < NBIN) ? binTotal[t] : 0;
    s[t] = v; __syncthreads();
    for (int off = 1; off < BLK; off <<= 1) {
        int tmp = (t >= off) ? s[t - off] : 0;
        __syncthreads();
        s[t] += tmp;
        __syncthreads();
    }
    if (t < NBIN) binBase[t] = s[t] - v;
    if (t == 0) binBase[NBIN] = s[BLK - 1];
}

__global__ __launch_bounds__(BLK) void fscatter_kernel(
    const int* __restrict__ rows, const int* __restrict__ cols, const float* __restrict__ vals,
    const float* __restrict__ dEflat, const int* __restrict__ binHist,
    const int* __restrict__ binBase, uint32* __restrict__ bm)
{
    __shared__ uint32 items[SC];
    __shared__ unsigned char bins[SC];
    __shared__ int hist[NBIN];
    __shared__ int cursor[NBIN];
    __shared__ int delta[NBIN];
    __shared__ int s[BLK];
    const int t = threadIdx.x, b = blockIdx.x;
    const int base = b * SC;
    const int nIt = min(SC, NNZ_ - base);
    const bool full = (base + SC <= NNZ_);

    if (t < NBIN) hist[t] = 0;
    __syncthreads();
    if (full) {
        const vi4* c4 = (const vi4*)(cols + base);
        #pragma unroll
        for (int j = 0; j < SC / (BLK * 4); ++j) {
            vi4 cc = __builtin_nontemporal_load(c4 + j * BLK + t);
            atomicAdd(&hist[cc.x >> CW_BITS], 1);
            atomicAdd(&hist[cc.y >> CW_BITS], 1);
            atomicAdd(&hist[cc.z >> CW_BITS], 1);
            atomicAdd(&hist[cc.w >> CW_BITS], 1);
        }
    } else {
        for (int j = 0; j < SC / BLK; ++j) {
            int k = base + j * BLK + t;
            if (k < NNZ_) atomicAdd(&hist[cols[k] >> CW_BITS], 1);
        }
    }
    __syncthreads();
    {
        int v = (t < NBIN) ? hist[t] : 0;
        s[t] = v; __syncthreads();
        for (int off = 1; off < BLK; off <<= 1) {
            int tmp = (t >= off) ? s[t - off] : 0;
            __syncthreads();
            s[t] += tmp;
            __syncthreads();
        }
        if (t < NBIN) {
            int ls = s[t] - v;
            cursor[t] = ls;
            delta[t]  = binBase[t] + binHist[t * NSB + b] - ls;
        }
    }
    __syncthreads();
    if (full) {
        const vi4* c4 = (const vi4*)(cols + base);
        const vi4* r4 = (const vi4*)(rows + base);
        const vf4* v4 = (const vf4*)(vals + base);
        #pragma unroll 2
        for (int j = 0; j < SC / (BLK * 4); ++j) {
            int idx = j * BLK + t;
            vi4 cc = __builtin_nontemporal_load(c4 + idx);
            vi4 rr = __builtin_nontemporal_load(r4 + idx);
            vf4 vv = __builtin_nontemporal_load(v4 + idx);
            float d0 = dEflat[rr.x];
            float d1 = dEflat[rr.y];
            float d2 = dEflat[rr.z];
            float d3 = dEflat[rr.w];
            #define PLACE(CI, VI, DI)                                              \
            {                                                                      \
                int bin = (CI) >> CW_BITS;                                         \
                uint32 u = __float_as_uint(-(VI) * (DI));                          \
                uint32 pk = ((uint32)((CI) & (CW - 1)) << 20)                      \
                            | ((u + 0x800u) >> 12);                                \
                int pos = atomicAdd(&cursor[bin], 1);                              \
                items[pos] = pk;                                                   \
                bins[pos] = (unsigned char)bin;                                    \
            }
            PLACE(cc.x, vv.x, d0)
            PLACE(cc.y, vv.y, d1)
            PLACE(cc.z, vv.z, d2)
            PLACE(cc.w, vv.w, d3)
        }
    } else {
        for (int j = 0; j < SC / BLK; ++j) {
            int k = base + j * BLK + t;
            if (k < NNZ_) {
                int c = cols[k];
                float d = dEflat[rows[k]];
                float v = vals[k];
                PLACE(c, v, d)
            }
        }
    }
    __syncthreads();
    for (int i = t; i < nIt; i += BLK) {
        __builtin_nontemporal_store(items[i], &bm[delta[bins[i]] + i]);
    }
}

__global__ __launch_bounds__(BLK) void fforce_kernel(
    const uint32* __restrict__ bm, const int* __restrict__ binBase,
    float* __restrict__ partial)
{
    __shared__ float w[CW];
    const int t = threadIdx.x;
    const int bin = blockIdx.x >> 3;
    const int sub = blockIdx.x & (SUBS - 1);
    for (int i = t; i < CW; i += BLK) w[i] = 0.0f;
    __syncthreads();
    const int start = binBase[bin];
    const int cnt   = binBase[bin + 1] - start;
    const int sBeg  = start + (cnt * sub) / SUBS;
    const int sEnd  = start + (cnt * (sub + 1)) / SUBS;
    int i = sBeg + t;
    for (; i + 3 * BLK < sEnd; i += 4 * BLK) {
        uint32 p0 = __builtin_nontemporal_load(bm + i);
        uint32 p1 = __builtin_nontemporal_load(bm + i + BLK);
        uint32 p2 = __builtin_nontemporal_load(bm + i + 2 * BLK);
        uint32 p3 = __builtin_nontemporal_load(bm + i + 3 * BLK);
        atomicAdd(&w[p0 >> 20], __uint_as_float((p0 & 0xFFFFFu) << 12));
        atomicAdd(&w[p1 >> 20], __uint_as_float((p1 & 0xFFFFFu) << 12));
        atomicAdd(&w[p2 >> 20], __uint_as_float((p2 & 0xFFFFFu) << 12));
        atomicAdd(&w[p3 >> 20], __uint_as_float((p3 & 0xFFFFFu) << 12));
    }
    for (; i < sEnd; i += BLK) {
        uint32 p = bm[i];
        atomicAdd(&w[p >> 20], __uint_as_float((p & 0xFFFFFu) << 12));
    }
    __syncthreads();
    float* dst = partial + (size_t)blockIdx.x * CW;
    for (int k = t; k < CW; k += BLK) __builtin_nontemporal_store(w[k], dst + k);
}

__global__ void force_kernel(const int* __restrict__ rows, const int* __restrict__ cols,
                             const float* __restrict__ vals, const float* __restrict__ dEflat,
                             float* __restrict__ force) {
    int k = blockIdx.x * blockDim.x + threadIdx.x;
    if (k < NNZ_) {
        float contrib = -vals[k] * dEflat[rows[k]];
        atomicAdd(&force[cols[k]], contrib);
    }
}

extern "C" void kernel_launch(void* const* d_in, const int* in_sizes, int n_in,
                              void* d_out, int out_size, void* d_ws, size_t ws_size,
                              hipStream_t stream) {
    (void)in_sizes; (void)n_in; (void)out_size;
    const float* fps  = (const float*)d_in[0];
    const float* W1   = (const float*)d_in[1];
    const float* b1   = (const float*)d_in[2];
    const float* W2   = (const float*)d_in[3];
    const float* b2   = (const float*)d_in[4];
    const float* W3   = (const float*)d_in[5];
    const float* b3   = (const float*)d_in[6];
    const int*   img  = (const int*)d_in[7];
    const int*   rows = (const int*)d_in[8];
    const int*   cols = (const int*)d_in[9];
    const float* vals = (const float*)d_in[10];

    char* ws = (char*)d_ws;
    float* energy = (float*)d_out;                   // [1800]
    float* force  = (float*)d_out + NIMG_;           // [540000]
    const int nOut = NIMG_ + 3 * QTOT;

    // v4 layout (fits known 208.4 MB floor):
    //   [0, 5.80 MB)      rank scratch  (dead after mlp)
    //   [0, 118.95 MB)    items uint2[55*CAPS]     (overlay; live after mlp)
    //   [0, 17.30 MB)     partial (overlay items; live after fscatter4)
    //   [118.95, 179.50)  bm uint32[132*CAPB]
    //   [179.50, 179.54)  ctrl
    //   [179.54, 208.34)  dEflat
    int*    g_hist  = (int*)(ws);
    int*    g_total = (int*)(ws + 5068800);
    int*    g_base  = (int*)(ws + 5076000);
    int*    rank    = (int*)(ws + 5083200);
    uint2*  items   = (uint2*)(ws);
    float*  partial4= (float*)(ws);
    uint32* bm4     = (uint32*)(ws + 118947840);
    int*    ctrl    = (int*)(ws + 179503104);
    float*  dEflat4 = (float*)(ws + 179536384);
    const size_t WS_V4 = 208336384;

    // R5 fallback layout
    float*  dEflat5   = (float*)(ws + 5803200);
    int*    binHist5  = (int*)(ws + 34603200);
    int*    binTotal5 = (int*)(ws + 35531424);
    int*    binBase5  = (int*)(ws + 35531952);
    uint32* bm5       = (uint32*)(ws + 35532496);
    float*  partial5  = (float*)(ws + 93132496);
    const size_t WS_V2 = 110434000;

    const bool v4 = (ws_size >= WS_V4);
    float* dEflat = v4 ? dEflat4 : dEflat5;

    zero_kernel<<<(nOut + BLK - 1) / BLK, BLK, 0, stream>>>((float*)d_out, nOut);

    // atom rank (stable argsort of image_idx)
    hist_kernel<<<NB, BLK, 0, stream>>>(img, g_hist);
    scan_blocks_kernel<<<NIMG_, BLK, 0, stream>>>(g_hist, g_total);
    scan_buckets_kernel<<<1, BLK, 0, stream>>>(g_total, g_base);
    rank_kernel<<<NB, BLK, 0, stream>>>(img, g_hist, g_base, rank);

    // per-atom MLP fwd+bwd
    dim3 gm((QE_ + BLK - 1) / BLK, E_);
    mlp_kernel<<<gm, BLK, 0, stream>>>(fps, W1, b1, W2, b2, W3, b3, img, rank,
                                       energy, dEflat);

    if (v4) {
        zero_ctrl_kernel<<<1, 256, 0, stream>>>(ctrl);
        slice_scatter_kernel<<<NSB, BLK, 0, stream>>>(rows, cols, vals, ctrl, items);
        plan4_kernel<<<1, BLK, 0, stream>>>(ctrl);
        fscatter4_kernel<<<FS_GRID, BLK, 0, stream>>>(items, dEflat, ctrl, bm4);
        fforce4_kernel<<<NBIN * SUBS, BLK, 0, stream>>>(bm4, ctrl, partial4);
        freduce_kernel<<<(3 * QTOT + BLK - 1) / BLK, BLK, 0, stream>>>(partial4, force);
    } else if (ws_size >= WS_V2) {
        fhist_kernel<<<NSB, BLK, 0, stream>>>(cols, binHist5);
        fscan_blocks_kernel<<<NBIN, BLK, 0, stream>>>(binHist5, binTotal5, NSB);
        fbase_kernel<<<1, BLK, 0, stream>>>(binTotal5, binBase5);
        fscatter_kernel<<<NSB, BLK, 0, stream>>>(rows, cols, vals, dEflat,
                                                 binHist5, binBase5, bm5);
        fforce_kernel<<<NBIN * SUBS, BLK, 0, stream>>>(bm5, binBase5, partial5);
        freduce_kernel<<<(3 * QTOT + BLK - 1) / BLK, BLK, 0, stream>>>(partial5, force);
    } else {
        force_kernel<<<NNZ_ / BLK, BLK, 0, stream>>>(rows, cols, vals, dEflat, force);
    }
}